// Round 1
// baseline (425.105 us; speedup 1.0000x reference)
//
#include <hip/hip_runtime.h>
#include <hip/hip_bf16.h>
#include <stdint.h>

#define WDIM 128
#define HID 256
#define G3 768
#define BATCH 4096
#define SEQ 32
#define BM 32
#define THREADS 512

// ws layout (ushort elems): WiT[768][128] @0, WhT[768][256] @98304, WpT[256][256] @294912
#define WS_WIT 0
#define WS_WHT 98304
#define WS_WPT 294912
#define WS_TOTAL 360448

typedef __attribute__((ext_vector_type(8))) short short8;
typedef __attribute__((ext_vector_type(4))) float f32x4;

#define MFMA(a, bfr, c) __builtin_amdgcn_mfma_f32_16x16x32_bf16((a), (bfr), (c), 0, 0, 0)

__device__ __forceinline__ ushort f2bf(float f) {
    union { float f; uint32_t u; } v; v.f = f;
    uint32_t u = v.u;
    u += 0x7fffu + ((u >> 16) & 1u);   // round-to-nearest-even
    return (ushort)(u >> 16);
}

__global__ void prep_kernel(const float* __restrict__ wi, const float* __restrict__ wh,
                            const float* __restrict__ wp, ushort* __restrict__ ws) {
    int gid = blockIdx.x * blockDim.x + threadIdx.x;
    if (gid < G3 * WDIM) {
        int n = gid / WDIM, k = gid % WDIM;
        ws[WS_WIT + n * WDIM + k] = f2bf(wi[k * G3 + n]);
    } else if (gid < G3 * WDIM + G3 * HID) {
        int g = gid - G3 * WDIM;
        int n = g / HID, k = g % HID;
        ws[WS_WHT + n * HID + k] = f2bf(wh[k * G3 + n]);
    } else if (gid < G3 * WDIM + G3 * HID + HID * HID) {
        int g = gid - G3 * WDIM - G3 * HID;
        int n = g / HID, k = g % HID;
        ws[WS_WPT + n * HID + k] = f2bf(wp[k * HID + n]);
    }
}

__global__ __launch_bounds__(THREADS, 2) void gru_kernel(
    const int* __restrict__ x, const float* __restrict__ embed,
    const float* __restrict__ bias, const float* __restrict__ bp,
    const ushort* __restrict__ WiT, const ushort* __restrict__ WhT,
    const ushort* __restrict__ WpT, float* __restrict__ out)
{
    __shared__ ushort xt[BM][136];     // bf16 x_t tile, padded (stride 272B -> 2-way banks)
    __shared__ ushort hbf[BM][264];    // bf16 h
    __shared__ ushort rh[BM][264];     // bf16 r*h
    __shared__ float  h32[BM][266];    // fp32 master h
    __shared__ float  biasS[G3 + HID];

    const int tid  = threadIdx.x;
    const int lane = tid & 63;
    const int wid  = tid >> 6;             // 8 waves
    const int lrow = lane & 15;
    const int kgrp = lane >> 4;
    const int r0   = blockIdx.x * BM;
    const int ncol0 = wid * (HID / 8);     // 32 hid-cols per wave

    for (int i = tid; i < BM * 266; i += THREADS) ((float*)h32)[i] = 0.f;
    for (int i = tid; i < BM * 264; i += THREADS) ((ushort*)hbf)[i] = 0;
    for (int i = tid; i < G3; i += THREADS)  biasS[i] = bias[i];
    for (int i = tid; i < HID; i += THREADS) biasS[G3 + i] = bp[i];

    for (int t = 0; t < SEQ; ++t) {
        __syncthreads();   // xt safe to overwrite; (first iter: covers LDS init)
        {   // gather embeddings for this step: 16 threads/row, 8 floats each
            int i = tid >> 4, c = tid & 15;
            int tok = x[(r0 + i) * SEQ + t];
            const float* e = embed + (size_t)tok * WDIM + c * 8;
            float4 f0 = ((const float4*)e)[0];
            float4 f1 = ((const float4*)e)[1];
            alignas(16) ushort tmp[8] = {f2bf(f0.x), f2bf(f0.y), f2bf(f0.z), f2bf(f0.w),
                                         f2bf(f1.x), f2bf(f1.y), f2bf(f1.z), f2bf(f1.w)};
            *(short8*)&xt[i][c * 8] = *(short8*)tmp;
        }
        __syncthreads();

        // ---- gates z, r : acc = xt@Wi + h@Wh ----
        f32x4 accz[2][2], accr[2][2];
        #pragma unroll
        for (int m = 0; m < 2; ++m)
            #pragma unroll
            for (int n = 0; n < 2; ++n) { accz[m][n] = (f32x4){0,0,0,0}; accr[m][n] = (f32x4){0,0,0,0}; }

        #pragma unroll
        for (int ks = 0; ks < 4; ++ks) {   // K = 128 from xt
            short8 a0 = *(const short8*)&xt[lrow][ks * 32 + kgrp * 8];
            short8 a1 = *(const short8*)&xt[16 + lrow][ks * 32 + kgrp * 8];
            #pragma unroll
            for (int n = 0; n < 2; ++n) {
                int col = ncol0 + n * 16 + lrow;
                short8 bz = *(const short8*)&WiT[(0 * HID + col) * WDIM + ks * 32 + kgrp * 8];
                short8 br = *(const short8*)&WiT[(1 * HID + col) * WDIM + ks * 32 + kgrp * 8];
                accz[0][n] = MFMA(a0, bz, accz[0][n]);
                accz[1][n] = MFMA(a1, bz, accz[1][n]);
                accr[0][n] = MFMA(a0, br, accr[0][n]);
                accr[1][n] = MFMA(a1, br, accr[1][n]);
            }
        }
        #pragma unroll
        for (int ks = 0; ks < 8; ++ks) {   // K = 256 from h
            short8 a0 = *(const short8*)&hbf[lrow][ks * 32 + kgrp * 8];
            short8 a1 = *(const short8*)&hbf[16 + lrow][ks * 32 + kgrp * 8];
            #pragma unroll
            for (int n = 0; n < 2; ++n) {
                int col = ncol0 + n * 16 + lrow;
                short8 bz = *(const short8*)&WhT[(0 * HID + col) * HID + ks * 32 + kgrp * 8];
                short8 br = *(const short8*)&WhT[(1 * HID + col) * HID + ks * 32 + kgrp * 8];
                accz[0][n] = MFMA(a0, bz, accz[0][n]);
                accz[1][n] = MFMA(a1, bz, accz[1][n]);
                accr[0][n] = MFMA(a0, br, accr[0][n]);
                accr[1][n] = MFMA(a1, br, accr[1][n]);
            }
        }

        // sigmoid; z stays in regs (accz), r*h -> LDS bf16
        #pragma unroll
        for (int m = 0; m < 2; ++m)
            #pragma unroll
            for (int n = 0; n < 2; ++n) {
                int col = ncol0 + n * 16 + lrow;
                #pragma unroll
                for (int j = 0; j < 4; ++j) {
                    int row = m * 16 + kgrp * 4 + j;
                    float zv = accz[m][n][j] + biasS[col];
                    zv = 1.f / (1.f + __expf(-zv));
                    accz[m][n][j] = zv;
                    float rv = accr[m][n][j] + biasS[HID + col];
                    rv = 1.f / (1.f + __expf(-rv));
                    rh[row][col] = f2bf(rv * h32[row][col]);
                }
            }
        __syncthreads();   // rh complete for all waves

        // ---- gate a : acc = xt@Wi_a + (r*h)@Wh_a ----
        f32x4 acca[2][2];
        #pragma unroll
        for (int m = 0; m < 2; ++m)
            #pragma unroll
            for (int n = 0; n < 2; ++n) acca[m][n] = (f32x4){0,0,0,0};

        #pragma unroll
        for (int ks = 0; ks < 4; ++ks) {
            short8 a0 = *(const short8*)&xt[lrow][ks * 32 + kgrp * 8];
            short8 a1 = *(const short8*)&xt[16 + lrow][ks * 32 + kgrp * 8];
            #pragma unroll
            for (int n = 0; n < 2; ++n) {
                int col = ncol0 + n * 16 + lrow;
                short8 ba = *(const short8*)&WiT[(2 * HID + col) * WDIM + ks * 32 + kgrp * 8];
                acca[0][n] = MFMA(a0, ba, acca[0][n]);
                acca[1][n] = MFMA(a1, ba, acca[1][n]);
            }
        }
        #pragma unroll
        for (int ks = 0; ks < 8; ++ks) {
            short8 a0 = *(const short8*)&rh[lrow][ks * 32 + kgrp * 8];
            short8 a1 = *(const short8*)&rh[16 + lrow][ks * 32 + kgrp * 8];
            #pragma unroll
            for (int n = 0; n < 2; ++n) {
                int col = ncol0 + n * 16 + lrow;
                short8 ba = *(const short8*)&WhT[(2 * HID + col) * HID + ks * 32 + kgrp * 8];
                acca[0][n] = MFMA(a0, ba, acca[0][n]);
                acca[1][n] = MFMA(a1, ba, acca[1][n]);
            }
        }

        // tanh + h update (each wave owns its cols)
        #pragma unroll
        for (int m = 0; m < 2; ++m)
            #pragma unroll
            for (int n = 0; n < 2; ++n) {
                int col = ncol0 + n * 16 + lrow;
                #pragma unroll
                for (int j = 0; j < 4; ++j) {
                    int row = m * 16 + kgrp * 4 + j;
                    float av = acca[m][n][j] + biasS[2 * HID + col];
                    float e2 = __expf(2.f * av);
                    av = (e2 - 1.f) / (e2 + 1.f);
                    float zv = accz[m][n][j];
                    float hn = (1.f - zv) * h32[row][col] + zv * av;
                    h32[row][col] = hn;
                    hbf[row][col] = f2bf(hn);
                }
            }
    }
    __syncthreads();   // h final complete

    // ---- projection: out = h @ w_p + b_p ----
    f32x4 accp[2][2];
    #pragma unroll
    for (int m = 0; m < 2; ++m)
        #pragma unroll
        for (int n = 0; n < 2; ++n) accp[m][n] = (f32x4){0,0,0,0};

    #pragma unroll
    for (int ks = 0; ks < 8; ++ks) {
        short8 a0 = *(const short8*)&hbf[lrow][ks * 32 + kgrp * 8];
        short8 a1 = *(const short8*)&hbf[16 + lrow][ks * 32 + kgrp * 8];
        #pragma unroll
        for (int n = 0; n < 2; ++n) {
            int col = ncol0 + n * 16 + lrow;
            short8 bb = *(const short8*)&WpT[col * HID + ks * 32 + kgrp * 8];
            accp[0][n] = MFMA(a0, bb, accp[0][n]);
            accp[1][n] = MFMA(a1, bb, accp[1][n]);
        }
    }
    #pragma unroll
    for (int m = 0; m < 2; ++m)
        #pragma unroll
        for (int n = 0; n < 2; ++n) {
            int col = ncol0 + n * 16 + lrow;
            #pragma unroll
            for (int j = 0; j < 4; ++j) {
                int row = m * 16 + kgrp * 4 + j;
                out[(size_t)(r0 + row) * HID + col] = accp[m][n][j] + biasS[G3 + col];
            }
        }
}

extern "C" void kernel_launch(void* const* d_in, const int* in_sizes, int n_in,
                              void* d_out, int out_size, void* d_ws, size_t ws_size,
                              hipStream_t stream) {
    const int*   x     = (const int*)d_in[0];
    const float* embed = (const float*)d_in[1];
    const float* wi    = (const float*)d_in[2];
    const float* wh    = (const float*)d_in[3];
    const float* b     = (const float*)d_in[4];
    const float* wp    = (const float*)d_in[5];
    const float* bp    = (const float*)d_in[6];
    float* out = (float*)d_out;
    ushort* ws = (ushort*)d_ws;

    hipLaunchKernelGGL(prep_kernel, dim3((WS_TOTAL + 255) / 256), dim3(256), 0, stream,
                       wi, wh, wp, ws);
    hipLaunchKernelGGL(gru_kernel, dim3(BATCH / BM), dim3(THREADS), 0, stream,
                       x, embed, b, bp, ws + WS_WIT, ws + WS_WHT, ws + WS_WPT, out);
}

// Round 2
// 295.981 us; speedup vs baseline: 1.4363x; 1.4363x over previous
//
#include <hip/hip_runtime.h>
#include <stdint.h>

#define WDIM 128
#define HID 256
#define G3 768
#define BATCH 4096
#define SEQ 32
#define BM 16
#define THREADS 512

// ws layout (ushort elems): WiT[768][128] @0, WhT[768][256] @98304, WpT[256][256] @294912
#define WS_WIT 0
#define WS_WHT 98304
#define WS_WPT 294912
#define WS_TOTAL 360448

// LDS byte offsets (dynamic smem)
#define L_WHA 0          // WhT_a swizzled [256 gatecols][512B]
#define L_XT  131072     // 2 x [16][256B] bf16 x_t, swizzled
#define L_HBF 139264     // [16][512B] bf16 h, swizzled
#define L_RH  147456     // [16][512B] bf16 r*h, swizzled
#define L_TOTAL 155648

typedef __attribute__((ext_vector_type(8))) short short8;
typedef __attribute__((ext_vector_type(4))) float f32x4;

#define MFMA(a, b, c) __builtin_amdgcn_mfma_f32_16x16x32_bf16((a), (b), (c), 0, 0, 0)

__device__ __forceinline__ ushort f2bf(float f) {
    union { float f; uint32_t u; } v; v.f = f;
    uint32_t u = v.u;
    u += 0x7fffu + ((u >> 16) & 1u);   // round-to-nearest-even
    return (ushort)(u >> 16);
}

__global__ void prep_kernel(const float* __restrict__ wi, const float* __restrict__ wh,
                            const float* __restrict__ wp, ushort* __restrict__ ws) {
    int gid = blockIdx.x * blockDim.x + threadIdx.x;
    if (gid < G3 * WDIM) {
        int n = gid / WDIM, k = gid % WDIM;
        ws[WS_WIT + n * WDIM + k] = f2bf(wi[k * G3 + n]);
    } else if (gid < G3 * WDIM + G3 * HID) {
        int g = gid - G3 * WDIM;
        int n = g / HID, k = g % HID;
        ws[WS_WHT + n * HID + k] = f2bf(wh[k * G3 + n]);
    } else if (gid < G3 * WDIM + G3 * HID + HID * HID) {
        int g = gid - G3 * WDIM - G3 * HID;
        int n = g / HID, k = g % HID;
        ws[WS_WPT + n * HID + k] = f2bf(wp[k * HID + n]);
    }
}

extern __shared__ char smem[];

__global__ __launch_bounds__(THREADS, 2) void gru_kernel(
    const int* __restrict__ x, const float* __restrict__ embed,
    const float* __restrict__ bias, const float* __restrict__ bp,
    const ushort* __restrict__ WiT, const ushort* __restrict__ WhT,
    const ushort* __restrict__ WpT, float* __restrict__ out)
{
    char* WhA = smem + L_WHA;
    char* XT  = smem + L_XT;
    char* HBF = smem + L_HBF;
    char* RH  = smem + L_RH;

    const int tid  = threadIdx.x;
    const int lane = tid & 63;
    const int wid  = tid >> 6;           // 8 waves
    const int lrow = lane & 15;
    const int kgrp = lane >> 4;
    const int r0   = blockIdx.x * BM;
    const int ncol0 = wid * 32;          // 32 gate/hid cols per wave
    const int grow = tid >> 5;           // gather: 16 rows x
    const int gq   = tid & 31;           //   32 float4-chunks

    // ---- one-time LDS fill: Wh_a swizzled ----
    for (int c = tid; c < 8192; c += THREADS) {     // 8192 chunks of 16B
        int row = c >> 5, ch = c & 31;
        short8 v = *(const short8*)&WhT[(size_t)(2 * HID + row) * HID + ch * 8];
        *(short8*)(WhA + row * 512 + ((ch * 16) ^ ((row & 7) << 4))) = v;
    }
    // zero h (bf16)
    *(short8*)(HBF + tid * 16) = (short8){0,0,0,0,0,0,0,0};
    // gather x_0 into XT buf0
    {
        int tok = x[(r0 + grow) * SEQ + 0];
        float4 f = *(const float4*)&embed[(size_t)tok * WDIM + gq * 4];
        uint32_t p0 = f2bf(f.x) | ((uint32_t)f2bf(f.y) << 16);
        uint32_t p1 = f2bf(f.z) | ((uint32_t)f2bf(f.w) << 16);
        *(uint2*)(XT + grow * 256 + ((gq * 8) ^ ((grow & 7) << 4))) = (uint2){p0, p1};
    }

    // ---- per-wave register cache: Wh z/r B-fragments (128 VGPR) ----
    short8 Wz[8][2], Wr[8][2];
    #pragma unroll
    for (int ks = 0; ks < 8; ++ks)
        #pragma unroll
        for (int n = 0; n < 2; ++n) {
            int colg = ncol0 + n * 16 + lrow;
            Wz[ks][n] = *(const short8*)&WhT[(size_t)colg * HID + ks * 32 + kgrp * 8];
            Wr[ks][n] = *(const short8*)&WhT[(size_t)(HID + colg) * HID + ks * 32 + kgrp * 8];
        }

    float bzr[2], brr[2], bar[2], bpr[2];
    #pragma unroll
    for (int n = 0; n < 2; ++n) {
        int colg = ncol0 + n * 16 + lrow;
        bzr[n] = bias[colg];
        brr[n] = bias[HID + colg];
        bar[n] = bias[2 * HID + colg];
        bpr[n] = bp[colg];
    }

    float h[2][4] = {{0.f,0.f,0.f,0.f},{0.f,0.f,0.f,0.f}};   // fp32 h in C-layout regs
    uint32_t zz = 0;                                          // anti-LICM token

    __syncthreads();

    for (int t = 0; t < SEQ; ++t) {
        char* xt = XT + (t & 1) * 4096;
        char* xn = XT + ((t + 1) & 1) * 4096;

        asm volatile("" : "+v"(zz));                 // make Wi loads loop-variant
        const ushort* wiB = WiT + zz;

        int tp = (t + 1 < SEQ) ? t + 1 : SEQ - 1;
        int tok = x[(r0 + grow) * SEQ + tp];         // issue token load early

        // ---- z/r GEMMs ----
        f32x4 az[2] = {{0,0,0,0},{0,0,0,0}};
        f32x4 ar[2] = {{0,0,0,0},{0,0,0,0}};

        #pragma unroll
        for (int ks = 0; ks < 4; ++ks) {             // K=128 from x_t, Wi streamed (L2)
            short8 a = *(const short8*)(xt + lrow * 256 + ((ks * 64 + kgrp * 16) ^ ((lrow & 7) << 4)));
            #pragma unroll
            for (int n = 0; n < 2; ++n) {
                int colg = ncol0 + n * 16 + lrow;
                short8 bz = *(const short8*)&wiB[(size_t)colg * WDIM + ks * 32 + kgrp * 8];
                short8 br = *(const short8*)&wiB[(size_t)(HID + colg) * WDIM + ks * 32 + kgrp * 8];
                az[n] = MFMA(a, bz, az[n]);
                ar[n] = MFMA(a, br, ar[n]);
            }
        }
        #pragma unroll
        for (int ks = 0; ks < 8; ++ks) {             // K=256 from h, Wh from regs
            short8 a = *(const short8*)(HBF + lrow * 512 + ((ks * 64 + kgrp * 16) ^ ((lrow & 7) << 4)));
            az[0] = MFMA(a, Wz[ks][0], az[0]);
            az[1] = MFMA(a, Wz[ks][1], az[1]);
            ar[0] = MFMA(a, Wr[ks][0], ar[0]);
            ar[1] = MFMA(a, Wr[ks][1], ar[1]);
        }

        // prefetch next-step embedding row (latency hides under epilogue + a-phase)
        float4 ef = *(const float4*)&embed[(size_t)tok * WDIM + gq * 4];

        // ---- epilogue z/r: sigmoid, r*h -> LDS ----
        #pragma unroll
        for (int n = 0; n < 2; ++n) {
            int colg = ncol0 + n * 16 + lrow;
            #pragma unroll
            for (int j = 0; j < 4; ++j) {
                int row = kgrp * 4 + j;
                float zv = az[n][j] + bzr[n];
                zv = 1.f / (1.f + __expf(-zv));
                az[n][j] = zv;                       // keep z in regs
                float rv = ar[n][j] + brr[n];
                rv = 1.f / (1.f + __expf(-rv));
                *(ushort*)(RH + row * 512 + ((colg * 2) ^ ((row & 7) << 4))) = f2bf(rv * h[n][j]);
            }
        }
        __syncthreads();

        // ---- a GEMM ----
        f32x4 aa[2] = {{0,0,0,0},{0,0,0,0}};
        #pragma unroll
        for (int ks = 0; ks < 4; ++ks) {             // x_t part, Wi_a streamed
            short8 a = *(const short8*)(xt + lrow * 256 + ((ks * 64 + kgrp * 16) ^ ((lrow & 7) << 4)));
            #pragma unroll
            for (int n = 0; n < 2; ++n) {
                int colg = ncol0 + n * 16 + lrow;
                short8 bw = *(const short8*)&wiB[(size_t)(2 * HID + colg) * WDIM + ks * 32 + kgrp * 8];
                aa[n] = MFMA(a, bw, aa[n]);
            }
        }
        #pragma unroll
        for (int ks = 0; ks < 8; ++ks) {             // (r*h) part, Wh_a from LDS
            short8 a = *(const short8*)(RH + lrow * 512 + ((ks * 64 + kgrp * 16) ^ ((lrow & 7) << 4)));
            #pragma unroll
            for (int n = 0; n < 2; ++n) {
                int colg = ncol0 + n * 16 + lrow;
                short8 bw = *(const short8*)(WhA + colg * 512 + ((ks * 64 + kgrp * 16) ^ ((colg & 7) << 4)));
                aa[n] = MFMA(a, bw, aa[n]);
            }
        }

        // ---- epilogue a: tanh, h update (regs) + hbf -> LDS ----
        #pragma unroll
        for (int n = 0; n < 2; ++n) {
            int colg = ncol0 + n * 16 + lrow;
            #pragma unroll
            for (int j = 0; j < 4; ++j) {
                int row = kgrp * 4 + j;
                float av = aa[n][j] + bar[n];
                float e2 = __expf(2.f * av);
                av = (e2 - 1.f) / (e2 + 1.f);
                float zv = az[n][j];
                float hn = (1.f - zv) * h[n][j] + zv * av;
                h[n][j] = hn;
                *(ushort*)(HBF + row * 512 + ((colg * 2) ^ ((row & 7) << 4))) = f2bf(hn);
            }
        }

        // write prefetched x_{t+1} into the other buffer
        {
            uint32_t p0 = f2bf(ef.x) | ((uint32_t)f2bf(ef.y) << 16);
            uint32_t p1 = f2bf(ef.z) | ((uint32_t)f2bf(ef.w) << 16);
            *(uint2*)(xn + grow * 256 + ((gq * 8) ^ ((grow & 7) << 4))) = (uint2){p0, p1};
        }
        __syncthreads();
    }

    // ---- projection: out = h @ w_p + b_p ----
    f32x4 ap[2] = {{0,0,0,0},{0,0,0,0}};
    #pragma unroll
    for (int ks = 0; ks < 8; ++ks) {
        short8 a = *(const short8*)(HBF + lrow * 512 + ((ks * 64 + kgrp * 16) ^ ((lrow & 7) << 4)));
        #pragma unroll
        for (int n = 0; n < 2; ++n) {
            int colg = ncol0 + n * 16 + lrow;
            short8 bw = *(const short8*)&WpT[(size_t)colg * HID + ks * 32 + kgrp * 8];
            ap[n] = MFMA(a, bw, ap[n]);
        }
    }
    #pragma unroll
    for (int n = 0; n < 2; ++n) {
        int colg = ncol0 + n * 16 + lrow;
        #pragma unroll
        for (int j = 0; j < 4; ++j) {
            int row = kgrp * 4 + j;
            out[(size_t)(r0 + row) * HID + colg] = ap[n][j] + bpr[n];
        }
    }
}

extern "C" void kernel_launch(void* const* d_in, const int* in_sizes, int n_in,
                              void* d_out, int out_size, void* d_ws, size_t ws_size,
                              hipStream_t stream) {
    const int*   x     = (const int*)d_in[0];
    const float* embed = (const float*)d_in[1];
    const float* wi    = (const float*)d_in[2];
    const float* wh    = (const float*)d_in[3];
    const float* b     = (const float*)d_in[4];
    const float* wp    = (const float*)d_in[5];
    const float* bp    = (const float*)d_in[6];
    float* out = (float*)d_out;
    ushort* ws = (ushort*)d_ws;

    // allow >64KB dynamic LDS (host-side state, not a stream op -> graph-safe)
    (void)hipFuncSetAttribute((const void*)gru_kernel,
                              hipFuncAttributeMaxDynamicSharedMemorySize, L_TOTAL);

    hipLaunchKernelGGL(prep_kernel, dim3((WS_TOTAL + 255) / 256), dim3(256), 0, stream,
                       wi, wh, wp, ws);
    hipLaunchKernelGGL(gru_kernel, dim3(BATCH / BM), dim3(THREADS), L_TOTAL, stream,
                       x, embed, b, bp, ws + WS_WIT, ws + WS_WHT, ws + WS_WPT, out);
}